// Round 1
// baseline (614.144 us; speedup 1.0000x reference)
//
#include <hip/hip_runtime.h>

#define DMODEL 512
#define NHEADS 8
#define DK 64
#define BSZ 4
#define NE 1024
#define NNODE 4096

typedef __attribute__((ext_vector_type(8))) __bf16 bf16x8;
typedef __attribute__((ext_vector_type(4))) float f32x4;
typedef __attribute__((ext_vector_type(8))) unsigned short u16x8;
typedef __attribute__((ext_vector_type(4))) unsigned short u16x4;

__device__ __forceinline__ unsigned short f2bf(float f) {
    union { float f; unsigned int u; } v; v.f = f;
    unsigned int u = v.u;
    return (unsigned short)((u + 0x7FFFu + ((u >> 16) & 1u)) >> 16);
}

__device__ __forceinline__ bf16x8 ldb8(const unsigned short* p) {
    return *reinterpret_cast<const bf16x8*>(p);
}

// ---------------- f32 -> bf16 conversion (vectorized, 8 elems/thread) ----------------
__global__ __launch_bounds__(256) void convk(const float4* __restrict__ src,
                                             u16x8* __restrict__ dst, int n8) {
    int i = blockIdx.x * 256 + threadIdx.x;
    if (i >= n8) return;
    float4 a = src[2 * i];
    float4 b = src[2 * i + 1];
    u16x8 o;
    o[0] = f2bf(a.x); o[1] = f2bf(a.y); o[2] = f2bf(a.z); o[3] = f2bf(a.w);
    o[4] = f2bf(b.x); o[5] = f2bf(b.y); o[6] = f2bf(b.z); o[7] = f2bf(b.w);
    dst[i] = o;
}

// ---------------- NT GEMM: C[m][n] = sum_k A[m][k] * W[n][k] + bias[n] ----------------
// A: M x 512 bf16 row-major.  W: 512 x 512 bf16 row-major.  K = N = 512.
// Block: 256 thr (4 waves), tile 64M x 128N; wave w owns rows w*16..w*16+15, all 128 cols.
// MODE 0: bf16 row-major out (M x 512)
// MODE 1: bf16 transposed V-layout out: Vt[(b*8+h)*64 + d][node], node-major (4096 wide)
// MODE 2: f32 row-major out (M x 512)
template <int MODE>
__global__ __launch_bounds__(256) void gemm_nt(const unsigned short* __restrict__ A,
                                               const unsigned short* __restrict__ W,
                                               const float* __restrict__ bias,
                                               void* __restrict__ Cout, int M) {
    const int K = DMODEL;
    int w = threadIdx.x >> 6, l = threadIdx.x & 63;
    int lr = l & 15, lh = l >> 4;
    int m0 = blockIdx.x * 64 + w * 16;
    int n0 = blockIdx.y * 128;

    f32x4 acc[8] = {};
    const unsigned short* Arow = A + (size_t)(m0 + lr) * K;

#pragma unroll 4
    for (int k0 = 0; k0 < K; k0 += 32) {
        bf16x8 a = ldb8(Arow + k0 + lh * 8);
#pragma unroll
        for (int t = 0; t < 8; ++t) {
            bf16x8 b = ldb8(W + (size_t)(n0 + t * 16 + lr) * K + k0 + lh * 8);
            acc[t] = __builtin_amdgcn_mfma_f32_16x16x32_bf16(a, b, acc[t], 0, 0, 0);
        }
    }

    if (MODE == 0) {
        unsigned short* C = (unsigned short*)Cout;
#pragma unroll
        for (int t = 0; t < 8; ++t) {
            float bv = bias[n0 + t * 16 + lr];
#pragma unroll
            for (int r = 0; r < 4; ++r) {
                C[(size_t)(m0 + lh * 4 + r) * DMODEL + n0 + t * 16 + lr] =
                    f2bf(acc[t][r] + bv);
            }
        }
    } else if (MODE == 1) {
        // rows of A are (b*4096 + node); cols are h*64 + d
        unsigned short* Vt = (unsigned short*)Cout;
        int bb = m0 >> 12;
        int node0 = (m0 & (NNODE - 1)) + lh * 4;
#pragma unroll
        for (int t = 0; t < 8; ++t) {
            int n = n0 + t * 16;
            int hh = n >> 6;
            int d = (n & 63) + lr;
            float bv = bias[n + lr];
            u16x4 pk;
#pragma unroll
            for (int r = 0; r < 4; ++r) pk[r] = f2bf(acc[t][r] + bv);
            *reinterpret_cast<u16x4*>(Vt + (size_t)((bb * NHEADS + hh) * DK + d) * NNODE +
                                      node0) = pk;
        }
    } else {
        float* C = (float*)Cout;
#pragma unroll
        for (int t = 0; t < 8; ++t) {
            float bv = bias[n0 + t * 16 + lr];
#pragma unroll
            for (int r = 0; r < 4; ++r) {
                C[(size_t)(m0 + lh * 4 + r) * DMODEL + n0 + t * 16 + lr] = acc[t][r] + bv;
            }
        }
    }
}

// ---------------- fused masked attention (flash-style, online softmax) ----------------
// Qb: (BS*E) x 512 bf16 ; Kb: (BS*N) x 512 bf16 ; Vt: (BS*8*64) x 4096 bf16
// inc: BS x E x N int32 ; Ob: (BS*E) x 512 bf16
// grid: (E/64, BS*H), block 256. Wave w owns 16 edge rows.
__global__ __launch_bounds__(256) void attn_kernel(const unsigned short* __restrict__ Qb,
                                                   const unsigned short* __restrict__ Kb,
                                                   const unsigned short* __restrict__ Vt,
                                                   const int* __restrict__ inc,
                                                   unsigned short* __restrict__ Ob) {
    int w = threadIdx.x >> 6, l = threadIdx.x & 63;
    int lr = l & 15, lh = l >> 4;
    int bh = blockIdx.y;
    int b = bh >> 3, h = bh & 7;
    int e0 = blockIdx.x * 64 + w * 16;

    __shared__ unsigned short Plds[4][16][72];  // +8 pad: 2-way-conflict b128 reads

    // Q fragments (A operand), hoisted: rows e0+lr, k = (0|32) + lh*8
    const unsigned short* Qrow = Qb + (size_t)(b * NE + e0 + lr) * DMODEL + h * DK;
    bf16x8 q0 = ldb8(Qrow + lh * 8);
    bf16x8 q1 = ldb8(Qrow + 32 + lh * 8);

    const unsigned short* Kbase = Kb + (size_t)b * NNODE * DMODEL + h * DK;
    const unsigned short* Vbase = Vt + (size_t)(bh * DK) * NNODE;
    const int* mbase = inc + (size_t)(b * NE + e0 + lh * 4) * NNODE;

    float mrun[4] = {-1e30f, -1e30f, -1e30f, -1e30f};
    float lrun[4] = {0.f, 0.f, 0.f, 0.f};
    f32x4 oacc[4] = {};

    for (int nb = 0; nb < NNODE; nb += 64) {
        // ---- S = Q K^T over this 64-node chunk: wave computes 16x64 ----
        f32x4 s[4] = {};
#pragma unroll
        for (int t = 0; t < 4; ++t) {
            const unsigned short* Krow = Kbase + (size_t)(nb + t * 16 + lr) * DMODEL;
            bf16x8 k0 = ldb8(Krow + lh * 8);
            bf16x8 k1 = ldb8(Krow + 32 + lh * 8);
            s[t] = __builtin_amdgcn_mfma_f32_16x16x32_bf16(q0, k0, s[t], 0, 0, 0);
            s[t] = __builtin_amdgcn_mfma_f32_16x16x32_bf16(q1, k1, s[t], 0, 0, 0);
        }
        // ---- mask + online softmax (rows = lh*4+r, cols = t*16+lr) ----
        float pv[4][4];  // [t][r]
        float scl[4];
#pragma unroll
        for (int r = 0; r < 4; ++r) {
            const int* mr = mbase + (size_t)r * NNODE + nb;
            float sr[4];
            float cm = -1e30f;
#pragma unroll
            for (int t = 0; t < 4; ++t) {
                int mv = mr[t * 16 + lr];
                float x = s[t][r] * 0.125f;
                x = (mv == 0) ? -1e9f : x;
                sr[t] = x;
                cm = fmaxf(cm, x);
            }
            cm = fmaxf(cm, __shfl_xor(cm, 1));
            cm = fmaxf(cm, __shfl_xor(cm, 2));
            cm = fmaxf(cm, __shfl_xor(cm, 4));
            cm = fmaxf(cm, __shfl_xor(cm, 8));
            float nm = fmaxf(mrun[r], cm);
            float sc = __expf(mrun[r] - nm);
            float ps = 0.f;
#pragma unroll
            for (int t = 0; t < 4; ++t) {
                float p = __expf(sr[t] - nm);
                pv[t][r] = p;
                ps += p;
            }
            ps += __shfl_xor(ps, 1);
            ps += __shfl_xor(ps, 2);
            ps += __shfl_xor(ps, 4);
            ps += __shfl_xor(ps, 8);
            lrun[r] = lrun[r] * sc + ps;
            mrun[r] = nm;
            scl[r] = sc;
        }
        // ---- rescale O accumulators ----
#pragma unroll
        for (int dt = 0; dt < 4; ++dt) {
#pragma unroll
            for (int r = 0; r < 4; ++r) oacc[dt][r] *= scl[r];
        }
        // ---- P -> LDS (bf16), re-layout for PV A operand ----
#pragma unroll
        for (int r = 0; r < 4; ++r) {
#pragma unroll
            for (int t = 0; t < 4; ++t) Plds[w][lh * 4 + r][t * 16 + lr] = f2bf(pv[t][r]);
        }
        // ---- O += P @ V  (B operand from Vt rows = contiguous) ----
#pragma unroll
        for (int kk = 0; kk < 2; ++kk) {
            bf16x8 pa = ldb8(&Plds[w][lr][kk * 32 + lh * 8]);
#pragma unroll
            for (int dt = 0; dt < 4; ++dt) {
                bf16x8 vb = ldb8(Vbase + (size_t)(dt * 16 + lr) * NNODE + nb + kk * 32 + lh * 8);
                oacc[dt] = __builtin_amdgcn_mfma_f32_16x16x32_bf16(pa, vb, oacc[dt], 0, 0, 0);
            }
        }
    }
    // ---- epilogue: O / l, store bf16 ----
#pragma unroll
    for (int r = 0; r < 4; ++r) {
        float inv = 1.0f / lrun[r];
        size_t row = (size_t)(b * NE + e0 + lh * 4 + r) * DMODEL + h * DK;
#pragma unroll
        for (int dt = 0; dt < 4; ++dt) {
            Ob[row + dt * 16 + lr] = f2bf(oacc[dt][r] * inv);
        }
    }
}

// ---------------- launch ----------------
extern "C" void kernel_launch(void* const* d_in, const int* in_sizes, int n_in,
                              void* d_out, int out_size, void* d_ws, size_t ws_size,
                              hipStream_t stream) {
    const float* queries = (const float*)d_in[0];
    const float* keys = (const float*)d_in[1];
    const int* inc = (const int*)d_in[2];
    const float* Wq = (const float*)d_in[3];
    const float* bq = (const float*)d_in[4];
    const float* Wk = (const float*)d_in[5];
    const float* bk = (const float*)d_in[6];
    const float* Wv = (const float*)d_in[7];
    const float* bv = (const float*)d_in[8];
    const float* Wo = (const float*)d_in[9];
    const float* bo = (const float*)d_in[10];

    unsigned short* ws = (unsigned short*)d_ws;
    unsigned short* qbf = ws;                                  // BS*E*512
    unsigned short* kbf = qbf + (size_t)BSZ * NE * DMODEL;     // BS*N*512
    unsigned short* wqb = kbf + (size_t)BSZ * NNODE * DMODEL;  // 512*512 x4
    unsigned short* wkb = wqb + DMODEL * DMODEL;
    unsigned short* wvb = wkb + DMODEL * DMODEL;
    unsigned short* wob = wvb + DMODEL * DMODEL;
    unsigned short* Qb = wob + DMODEL * DMODEL;               // BS*E*512
    unsigned short* Kb = Qb + (size_t)BSZ * NE * DMODEL;      // BS*N*512
    unsigned short* Vt = Kb + (size_t)BSZ * NNODE * DMODEL;   // BS*8*64 x 4096
    unsigned short* Ob = Vt + (size_t)BSZ * NNODE * DMODEL;   // BS*E*512

    auto conv = [&](const float* s, unsigned short* d, int n) {
        int n8 = n / 8;
        convk<<<dim3((n8 + 255) / 256), 256, 0, stream>>>((const float4*)s, (u16x8*)d, n8);
    };
    conv(queries, qbf, BSZ * NE * DMODEL);
    conv(keys, kbf, BSZ * NNODE * DMODEL);
    conv(Wq, wqb, DMODEL * DMODEL);
    conv(Wk, wkb, DMODEL * DMODEL);
    conv(Wv, wvb, DMODEL * DMODEL);
    conv(Wo, wob, DMODEL * DMODEL);

    gemm_nt<0><<<dim3(BSZ * NE / 64, DMODEL / 128), 256, 0, stream>>>(qbf, wqb, bq, Qb,
                                                                      BSZ * NE);
    gemm_nt<0><<<dim3(BSZ * NNODE / 64, DMODEL / 128), 256, 0, stream>>>(kbf, wkb, bk, Kb,
                                                                         BSZ * NNODE);
    gemm_nt<1><<<dim3(BSZ * NNODE / 64, DMODEL / 128), 256, 0, stream>>>(kbf, wvb, bv, Vt,
                                                                         BSZ * NNODE);

    attn_kernel<<<dim3(NE / 64, BSZ * NHEADS), 256, 0, stream>>>(Qb, Kb, Vt, inc, Ob);

    gemm_nt<2><<<dim3(BSZ * NE / 64, DMODEL / 128), 256, 0, stream>>>(Ob, wob, bo, d_out,
                                                                      BSZ * NE);
}